// Round 1
// baseline (158.839 us; speedup 1.0000x reference)
//
#include <hip/hip_runtime.h>

// CustomEmbedding: out[i,:] = weight[:, index[i]]
//   index : int32 [4096*200]      (in_sizes[0] = 819200)
//   weight: float32 [128][100000] (in_sizes[1] = 12800000)
//   out   : float32 [819200][128]

#define EMB_V 100000
#define EMB_D 128

// --- Kernel 1: transpose weight [D][V] -> table [V][D] (coalesced both sides)
__global__ void __launch_bounds__(256)
emb_transpose_kernel(const float* __restrict__ w, float* __restrict__ t) {
    __shared__ float tile[32][33];              // +1 pad: conflict-free
    const int tv = blockIdx.x * 32;             // v-tile base (100000 = 3125*32)
    const int td = blockIdx.y * 32;             // d-tile base (128 = 4*32)
    const int lx = threadIdx.x;                 // 0..31
    const int ly = threadIdx.y;                 // 0..7
#pragma unroll
    for (int i = ly; i < 32; i += 8)
        tile[i][lx] = w[(size_t)(td + i) * EMB_V + (tv + lx)];   // coalesced in v
    __syncthreads();
#pragma unroll
    for (int i = ly; i < 32; i += 8)
        t[(size_t)(tv + i) * EMB_D + (td + lx)] = tile[lx][i];   // coalesced in d
}

// --- Kernel 2: gather rows of table; one float4 per thread (32 f4 per row)
__global__ void __launch_bounds__(256)
emb_gather_kernel(const float4* __restrict__ table, const int* __restrict__ idx,
                  float4* __restrict__ out, long n4) {
    const long stride = (long)gridDim.x * blockDim.x;
    for (long g = (long)blockIdx.x * blockDim.x + threadIdx.x; g < n4; g += stride) {
        const long row = g >> 5;                // / 32 float4 per row
        const int  j   = (int)(g & 31);
        const int  v   = idx[row];
        out[g] = table[(size_t)v * 32 + j];     // contiguous 512B per row
    }
}

// --- Fallback (no workspace): direct strided gather from weight [D][V]
__global__ void __launch_bounds__(256)
emb_gather_direct_kernel(const float* __restrict__ w, const int* __restrict__ idx,
                         float* __restrict__ out, long n) {
    const long stride = (long)gridDim.x * blockDim.x;
    for (long g = (long)blockIdx.x * blockDim.x + threadIdx.x; g < n; g += stride) {
        const long row = g >> 7;                // / 128
        const int  d   = (int)(g & 127);
        const int  v   = idx[row];
        out[g] = w[(size_t)d * EMB_V + v];
    }
}

extern "C" void kernel_launch(void* const* d_in, const int* in_sizes, int n_in,
                              void* d_out, int out_size, void* d_ws, size_t ws_size,
                              hipStream_t stream) {
    const int*   idx = (const int*)d_in[0];
    const float* w   = (const float*)d_in[1];
    float*       out = (float*)d_out;

    const long n_rows = (long)in_sizes[0];            // 819200
    const long n_elem = n_rows * EMB_D;               // 104,857,600
    const size_t table_bytes = (size_t)EMB_V * EMB_D * sizeof(float);  // 51.2 MB

    if (ws_size >= table_bytes) {
        float* table = (float*)d_ws;
        dim3 tgrid(EMB_V / 32, EMB_D / 32);           // (3125, 4)
        dim3 tblock(32, 8);
        emb_transpose_kernel<<<tgrid, tblock, 0, stream>>>(w, table);

        const long n4 = n_elem / 4;                   // 26,214,400 float4
        emb_gather_kernel<<<2048, 256, 0, stream>>>(
            (const float4*)table, idx, (float4*)out, n4);
    } else {
        emb_gather_direct_kernel<<<2048, 256, 0, stream>>>(w, idx, out, n_elem);
    }
}

// Round 2
// 151.293 us; speedup vs baseline: 1.0499x; 1.0499x over previous
//
#include <hip/hip_runtime.h>

// CustomEmbedding: out[i,:] = weight[:, index[i]]
//   index : int32 [4096*200]      (in_sizes[0] = 819200)
//   weight: float32 [128][100000] (in_sizes[1] = 12800000)
//   out   : float32 [819200][128]

#define EMB_V 100000
#define EMB_D 128

typedef float vf4 __attribute__((ext_vector_type(4)));

// --- Kernel 1: transpose weight [D][V] -> table [V][D].
// One block per 32-wide vocab tile; covers all 128 d.
// Reads: nontemporal (weight is read-once; don't pollute L3 — we want the
// TABLE resident there). Writes: normal/cached (table reused 8.2x by gather).
__global__ void __launch_bounds__(256)
emb_transpose_kernel(const float* __restrict__ w, float* __restrict__ t) {
    __shared__ float tile[32][132];             // 132: 16B-aligned rows (528B), breaks pow2
    const int tv = blockIdx.x * 32;             // v-tile base (100000 = 3125*32)
    const int lx = threadIdx.x & 31;            // v within tile
    const int ly = threadIdx.x >> 5;            // 0..7
    // read phase: w[d][tv+lx], coalesced 128B per 32 lanes
#pragma unroll
    for (int d = ly; d < EMB_D; d += 8)
        tile[lx][d] = __builtin_nontemporal_load(&w[(size_t)d * EMB_V + (tv + lx)]);
    __syncthreads();
    // write phase: full 512B table rows as float4
#pragma unroll
    for (int q = threadIdx.x; q < 32 * 32; q += 256) {
        const int r = q >> 5;                   // v row in tile
        const int c = q & 31;                   // float4 column (128 floats = 32 f4)
        vf4 val = *(const vf4*)&tile[r][c * 4]; // aligned: row stride 528B
        *(vf4*)&t[(size_t)(tv + r) * EMB_D + c * 4] = val;  // cached store
    }
}

// --- Kernel 2: gather rows of table; one float4 per thread (32 f4 per row).
// Table reads cached (L3-resident, 51.2MB); output stores NONTEMPORAL so the
// 419MB write stream does not evict the table.
__global__ void __launch_bounds__(256)
emb_gather_kernel(const vf4* __restrict__ table, const int* __restrict__ idx,
                  vf4* __restrict__ out, long n4) {
    const long stride = (long)gridDim.x * blockDim.x;
    for (long g = (long)blockIdx.x * blockDim.x + threadIdx.x; g < n4; g += stride) {
        const long row = g >> 5;                // / 32 float4 per row
        const int  j   = (int)(g & 31);
        const int  v   = idx[row];
        vf4 val = table[(size_t)v * 32 + j];    // contiguous 512B per row, L3 hit
        __builtin_nontemporal_store(val, &out[g]);
    }
}

// --- Fallback (no workspace): direct strided gather from weight [D][V]
__global__ void __launch_bounds__(256)
emb_gather_direct_kernel(const float* __restrict__ w, const int* __restrict__ idx,
                         float* __restrict__ out, long n) {
    const long stride = (long)gridDim.x * blockDim.x;
    for (long g = (long)blockIdx.x * blockDim.x + threadIdx.x; g < n; g += stride) {
        const long row = g >> 7;                // / 128
        const int  d   = (int)(g & 127);
        const int  v   = idx[row];
        __builtin_nontemporal_store(w[(size_t)d * EMB_V + v], &out[g]);
    }
}

extern "C" void kernel_launch(void* const* d_in, const int* in_sizes, int n_in,
                              void* d_out, int out_size, void* d_ws, size_t ws_size,
                              hipStream_t stream) {
    const int*   idx = (const int*)d_in[0];
    const float* w   = (const float*)d_in[1];

    const long n_rows = (long)in_sizes[0];            // 819200
    const long n_elem = n_rows * EMB_D;               // 104,857,600
    const size_t table_bytes = (size_t)EMB_V * EMB_D * sizeof(float);  // 51.2 MB

    if (ws_size >= table_bytes) {
        float* table = (float*)d_ws;
        emb_transpose_kernel<<<EMB_V / 32, 256, 0, stream>>>(w, table);

        const long n4 = n_elem / 4;                   // 26,214,400 float4
        emb_gather_kernel<<<4096, 256, 0, stream>>>(
            (const vf4*)table, idx, (vf4*)d_out, n4);
    } else {
        emb_gather_direct_kernel<<<4096, 256, 0, stream>>>(w, idx, (float*)d_out, n_elem);
    }
}